// Round 8
// baseline (54.021 us; speedup 1.0000x reference)
//
#include <hip/hip_runtime.h>

// GeometryKernelAttention: nearest-neighbor multi-scale gather + weighted sum.
// B=1, NQ=20000, H=8, L=4, P=8, D=32, NUM_VALUE=19560.
// Output: (1, 20000, 256) f32, returned twice (concatenated in d_out).
//
// R2: head<->XCD affinity (blockIdx%8 == head) -> per-head 2.45 MB value slice
//     is L2-resident per XCD; FETCH_SIZE at the 50 MB compulsory ideal.
// R3-R6 (all reverted): fw-in-LDS null; bf16 gather null (bytes don't matter);
//     L2+L3/L3 LDS staging + deep MLP regressions (staging consumes the same
//     L1-miss-path slots; VGPR>64 halves occupancy).
// Conclusion: pinned at ~116 G random line-requests/s = per-CU MSHR x L2-hit
//     latency wall (~40 outstanding fills x ~210 cy). Request count (5.12 M)
//     is irreducible for uniform-random locations.
// R7/R8: best structure (R2) + non-temporal hints on the streaming arrays
//     (loc/weight reads, output writes) to keep them out of the value L2 set.
//     (R8 fixes the builtin's pointer-type requirement: ext_vector_type.)

#define GKA_NQ       20000
#define GKA_H        8
#define GKA_NV       19560
#define GKA_OUT_HALF 5120000   // 20000 * 256

typedef float vf4 __attribute__((ext_vector_type(4)));

__global__ __launch_bounds__(256) void gka_kernel(
    const float* __restrict__ value,   // [NV, 8, 32] (b=1)
    const float* __restrict__ sloc,    // [NQ, 8, 4, 8, 2]
    const float* __restrict__ awgt,    // [NQ, 8, 4, 8]
    float* __restrict__ out)           // [2, NQ, 256]
{
    const int tid  = threadIdx.x;
    const int lane = tid & 63;
    const int wave = tid >> 6;                 // 0..3
    const int h      = blockIdx.x & 7;         // head == XCD (round-robin dispatch)
    const int qchunk = blockIdx.x >> 3;
    const int qq   = lane >> 3;                // query within wave: 0..7
    const int sub  = lane & 7;                 // d-quad owner within (q,h)
    const int q    = qchunk * 32 + wave * 8 + qq;

    // ---- Phase A: this lane computes samples j = 4*sub .. 4*sub+3 ----
    // 4 consecutive samples always lie in the same level: lvl = sub >> 1.
    const int lvl = sub >> 1;
    const int Wi  = (lvl == 0) ? 160 : (lvl == 1) ? 80 : (lvl == 2) ? 40 : 20;
    const int Hi  = (lvl == 0) ? 92  : (lvl == 1) ? 46 : (lvl == 2) ? 23 : 12;
    const int ls  = (lvl == 0) ? 0   : (lvl == 1) ? 14720 : (lvl == 2) ? 18400 : 19320;
    const float Wf = (float)Wi;
    const float Hf = (float)Hi;

    const int qh = q * GKA_H + h;
    const vf4* lp = (const vf4*)(sloc + (size_t)qh * 64 + sub * 8);
    const vf4 xy0 = __builtin_nontemporal_load(lp);
    const vf4 xy1 = __builtin_nontemporal_load(lp + 1);
    const vf4 w4  = __builtin_nontemporal_load(
                        (const vf4*)(awgt + (size_t)qh * 32 + sub * 4));

    int   fl[4];
    float wk[4];
    {
        const float xs[4] = {xy0.x, xy0.z, xy1.x, xy1.z};
        const float ys[4] = {xy0.y, xy0.w, xy1.y, xy1.w};
        const float ws[4] = {w4.x, w4.y, w4.z, w4.w};
        #pragma unroll
        for (int k = 0; k < 4; ++k) {
            const int col = (int)floorf(xs[k] * Wf);
            const int row = (int)floorf(ys[k] * Hf);
            const bool valid = (col >= 0) & (col < Wi) & (row >= 0) & (row < Hi);
            int f = ls + row * Wi + col;
            f = min(max(f, 0), GKA_NV - 1);
            fl[k] = f;
            wk[k] = valid ? ws[k] : 0.0f;
        }
    }

    // ---- Phase B: broadcast (flat, w) within 8-lane group, gather+FMA ----
    float4 acc = make_float4(0.f, 0.f, 0.f, 0.f);
    const float* vbase = value + h * 32 + sub * 4;  // + flat*256 per sample
    const int gbase = lane & 56;                    // group base lane
    #pragma unroll
    for (int j = 0; j < 32; ++j) {
        const int src = gbase | (j >> 2);
        const int   f = __shfl(fl[j & 3], src, 64);
        const float w = __shfl(wk[j & 3], src, 64);
        const float4 v = *(const float4*)(vbase + (size_t)f * 256);
        acc.x = fmaf(w, v.x, acc.x);
        acc.y = fmaf(w, v.y, acc.y);
        acc.z = fmaf(w, v.z, acc.z);
        acc.w = fmaf(w, v.w, acc.w);
    }

    // ---- Write both tuple outputs (identical), non-temporal ----
    float* o = out + (size_t)q * 256 + h * 32 + sub * 4;
    vf4 accv;
    accv.x = acc.x; accv.y = acc.y; accv.z = acc.z; accv.w = acc.w;
    __builtin_nontemporal_store(accv, (vf4*)o);
    __builtin_nontemporal_store(accv, (vf4*)(o + GKA_OUT_HALF));
}

extern "C" void kernel_launch(void* const* d_in, const int* in_sizes, int n_in,
                              void* d_out, int out_size, void* d_ws, size_t ws_size,
                              hipStream_t stream) {
    const float* value = (const float*)d_in[0];
    // d_in[1] = spatial_shapes, d_in[2] = level_start_index: compile-time constants.
    const float* sloc  = (const float*)d_in[3];
    const float* awgt  = (const float*)d_in[4];
    float* out = (float*)d_out;

    // 625 query-chunks x 8 heads; blockIdx % 8 == head -> XCD affinity.
    dim3 grid((GKA_NQ / 32) * GKA_H);
    gka_kernel<<<grid, 256, 0, stream>>>(value, sloc, awgt, out);
}

// Round 9
// 44.510 us; speedup vs baseline: 1.2137x; 1.2137x over previous
//
#include <hip/hip_runtime.h>

// GeometryKernelAttention: nearest-neighbor multi-scale gather + weighted sum.
// B=1, NQ=20000, H=8, L=4, P=8, D=32, NUM_VALUE=19560.
// Output: (1, 20000, 256) f32, returned twice (concatenated in d_out).
//
// FINAL (R9 = R2 revert). Ladder:
//   R1 naive-coalesced: 62.7 us, FETCH 181 MB (L2-miss over-fetch).
//   R2 head<->XCD affinity (blockIdx%8==head): 44.5 us, FETCH at 50 MB ideal.
//   R3 fw-in-LDS: null -> not front-end bound.
//   R4 bf16 gather (half bytes): null -> request-count bound, not bytes.
//   R5/R6 LDS staging + forced MLP: regressions (staging shares the same
//       request path; VGPR>64 halves occupancy).
//   R8 non-temporal hints: regression (NT store path).
// Roofline: 5.12M random 128-B aligned line-requests / 44.5 us = 115 G lines/s
//   = 1.84 TB/s per XCD L2 ~= 43% of streaming ceiling (random bank-collision
//   penalty). No lever reduces line count for uniform-random locations.

#define GKA_NQ       20000
#define GKA_H        8
#define GKA_NV       19560
#define GKA_OUT_HALF 5120000   // 20000 * 256

__global__ __launch_bounds__(256) void gka_kernel(
    const float* __restrict__ value,   // [NV, 8, 32] (b=1)
    const float* __restrict__ sloc,    // [NQ, 8, 4, 8, 2]
    const float* __restrict__ awgt,    // [NQ, 8, 4, 8]
    float* __restrict__ out)           // [2, NQ, 256]
{
    const int tid  = threadIdx.x;
    const int lane = tid & 63;
    const int wave = tid >> 6;                 // 0..3
    const int h      = blockIdx.x & 7;         // head == XCD (round-robin dispatch)
    const int qchunk = blockIdx.x >> 3;
    const int qq   = lane >> 3;                // query within wave: 0..7
    const int sub  = lane & 7;                 // d-quad owner within (q,h)
    const int q    = qchunk * 32 + wave * 8 + qq;

    // ---- Phase A: this lane computes samples j = 4*sub .. 4*sub+3 ----
    // 4 consecutive samples always lie in the same level: lvl = sub >> 1.
    const int lvl = sub >> 1;
    const int Wi  = (lvl == 0) ? 160 : (lvl == 1) ? 80 : (lvl == 2) ? 40 : 20;
    const int Hi  = (lvl == 0) ? 92  : (lvl == 1) ? 46 : (lvl == 2) ? 23 : 12;
    const int ls  = (lvl == 0) ? 0   : (lvl == 1) ? 14720 : (lvl == 2) ? 18400 : 19320;
    const float Wf = (float)Wi;
    const float Hf = (float)Hi;

    const int qh = q * GKA_H + h;
    const float4* lp = (const float4*)(sloc + (size_t)qh * 64 + sub * 8);
    const float4 xy0 = lp[0];
    const float4 xy1 = lp[1];
    const float4 w4  = *(const float4*)(awgt + (size_t)qh * 32 + sub * 4);

    int   fl[4];
    float wk[4];
    {
        const float xs[4] = {xy0.x, xy0.z, xy1.x, xy1.z};
        const float ys[4] = {xy0.y, xy0.w, xy1.y, xy1.w};
        const float ws[4] = {w4.x, w4.y, w4.z, w4.w};
        #pragma unroll
        for (int k = 0; k < 4; ++k) {
            const int col = (int)floorf(xs[k] * Wf);
            const int row = (int)floorf(ys[k] * Hf);
            const bool valid = (col >= 0) & (col < Wi) & (row >= 0) & (row < Hi);
            int f = ls + row * Wi + col;
            f = min(max(f, 0), GKA_NV - 1);
            fl[k] = f;
            wk[k] = valid ? ws[k] : 0.0f;
        }
    }

    // ---- Phase B: broadcast (flat, w) within 8-lane group, gather+FMA ----
    float4 acc = make_float4(0.f, 0.f, 0.f, 0.f);
    const float* vbase = value + h * 32 + sub * 4;  // + flat*256 per sample
    const int gbase = lane & 56;                    // group base lane
    #pragma unroll
    for (int j = 0; j < 32; ++j) {
        const int src = gbase | (j >> 2);
        const int   f = __shfl(fl[j & 3], src, 64);
        const float w = __shfl(wk[j & 3], src, 64);
        const float4 v = *(const float4*)(vbase + (size_t)f * 256);
        acc.x = fmaf(w, v.x, acc.x);
        acc.y = fmaf(w, v.y, acc.y);
        acc.z = fmaf(w, v.z, acc.z);
        acc.w = fmaf(w, v.w, acc.w);
    }

    // ---- Write both tuple outputs (identical) ----
    float* o = out + (size_t)q * 256 + h * 32 + sub * 4;
    *(float4*)o = acc;
    *(float4*)(o + GKA_OUT_HALF) = acc;
}

extern "C" void kernel_launch(void* const* d_in, const int* in_sizes, int n_in,
                              void* d_out, int out_size, void* d_ws, size_t ws_size,
                              hipStream_t stream) {
    const float* value = (const float*)d_in[0];
    // d_in[1] = spatial_shapes, d_in[2] = level_start_index: compile-time constants.
    const float* sloc  = (const float*)d_in[3];
    const float* awgt  = (const float*)d_in[4];
    float* out = (float*)d_out;

    // 625 query-chunks x 8 heads; blockIdx % 8 == head -> XCD affinity.
    dim3 grid((GKA_NQ / 32) * GKA_H);
    gka_kernel<<<grid, 256, 0, stream>>>(value, sloc, awgt, out);
}